// Round 14
// baseline (114.201 us; speedup 1.0000x reference)
//
#include <hip/hip_runtime.h>

#define TPB 256

// Fused CIoU, 1 thread/element — r13 baseline (clean 116-VGPR allocation)
// + ONE strictly LOCAL delta: the Jarvis scan is split into two independent
// 8-point chains (A-side / B-side), each seeded with -din, merged by one
// cross-compare. Halves the march's serial cmp->cndmask critical path
// (16 links -> 8+1), which round-13 arithmetic identifies as the limiter
// (clip chain already has 16-edge ILP; march has none).
// Tie (cr==0) keeps the A-side candidate == serial A-first scan order.
// Codegen law (r3/r4/r6/r7/r8/r9/r12): serial chains + block-local temps,
// TPB=256, shuffles only in the epilogue. No arrays, no in-loop shuffles,
// no cross-block hoists, no 64-thread blocks.
__global__ __launch_bounds__(TPB, 2) void ciou_fused(
    const float* __restrict__ A,
    const float* __restrict__ Bq,
    float* __restrict__ out,
    double* __restrict__ acc,
    unsigned int* __restrict__ cnt,
    int nbatch, int nblocks)
{
    const int t = threadIdx.x;
    const int i0 = blockIdx.x * TPB + t;
    const bool live = (i0 < nbatch);
    const int i = live ? i0 : (nbatch - 1);

    float ax0,ax1,ax2,ax3,ax4,ax5,ax6,ax7;
    float ay0,ay1,ay2,ay3,ay4,ay5,ay6,ay7;
    float bx0,bx1,bx2,bx3,bx4,bx5,bx6,bx7;
    float by0,by1,by2,by3,by4,by5,by6,by7;
    {
        const float4* pa = (const float4*)(A + (size_t)i * 16);
        const float4* pb = (const float4*)(Bq + (size_t)i * 16);
        float4 q;
        q = pa[0]; ax0=q.x; ay0=q.y; ax1=q.z; ay1=q.w;
        q = pa[1]; ax2=q.x; ay2=q.y; ax3=q.z; ay3=q.w;
        q = pa[2]; ax4=q.x; ay4=q.y; ax5=q.z; ay5=q.w;
        q = pa[3]; ax6=q.x; ay6=q.y; ax7=q.z; ay7=q.w;
        q = pb[0]; bx0=q.x; by0=q.y; bx1=q.z; by1=q.w;
        q = pb[1]; bx2=q.x; by2=q.y; bx3=q.z; by3=q.w;
        q = pb[2]; bx4=q.x; by4=q.y; bx5=q.z; by5=q.w;
        q = pb[3]; bx6=q.x; by6=q.y; bx7=q.z; by7=q.w;
    }

    // Shoelace areas (input vertex order is CCW; sort_poly = rotation).
    float area_a = 0.5f * ((ax0*ay1-ay0*ax1) + (ax1*ay2-ay1*ax2)
                         + (ax2*ay3-ay2*ax3) + (ax3*ay4-ay3*ax4)
                         + (ax4*ay5-ay4*ax5) + (ax5*ay6-ay5*ax6)
                         + (ax6*ay7-ay6*ax7) + (ax7*ay0-ay7*ax0));
    float area_b = 0.5f * ((bx0*by1-by0*bx1) + (bx1*by2-by1*bx2)
                         + (bx2*by3-by2*bx3) + (bx3*by4-by3*bx4)
                         + (bx4*by5-by4*bx5) + (bx5*by6-by5*bx6)
                         + (bx6*by7-by6*bx7) + (bx7*by0-by7*bx0));

    // ---- Intersection: Green's theorem over clipped edges ----
    float inter2 = 0.f;

    // inside Q iff cross(E_Q, p - V_Q) >= 0; along edge: aa + t*bb >= 0.
    // Branchless: h = bb*1e38 (+big if bb>0, -big if bb<0); IEEE min/max
    // absorb the unused arm. bb==0 (parallel) is measure-zero (r10+ absmax 0).
#define HP(T0,T1,QX0,QY0,QX1,QY1) { \
        float ex = (QX1)-(QX0), ey = (QY1)-(QY0); \
        float aa = ex*(Py-(QY0)) - ey*(Px-(QX0)); \
        float bb = ex*Dy - ey*Dx; \
        float tc = __fdividef(-aa, bb); \
        float h = bb * 1e38f; \
        T0 = fmaxf(T0, fminf(tc, h)); \
        T1 = fminf(T1, fmaxf(tc, h)); }

#define HPB HP(t0a,t1a,bx0,by0,bx1,by1) HP(t0b,t1b,bx1,by1,bx2,by2) \
            HP(t0a,t1a,bx2,by2,bx3,by3) HP(t0b,t1b,bx3,by3,bx4,by4) \
            HP(t0a,t1a,bx4,by4,bx5,by5) HP(t0b,t1b,bx5,by5,bx6,by6) \
            HP(t0a,t1a,bx6,by6,bx7,by7) HP(t0b,t1b,bx7,by7,bx0,by0)
#define HPA HP(t0a,t1a,ax0,ay0,ax1,ay1) HP(t0b,t1b,ax1,ay1,ax2,ay2) \
            HP(t0a,t1a,ax2,ay2,ax3,ay3) HP(t0b,t1b,ax3,ay3,ax4,ay4) \
            HP(t0a,t1a,ax4,ay4,ax5,ay5) HP(t0b,t1b,ax5,ay5,ax6,ay6) \
            HP(t0a,t1a,ax6,ay6,ax7,ay7) HP(t0b,t1b,ax7,ay7,ax0,ay0)

    // cross(P(t0),P(t1)) = (t1-t0)*cross(P,D) ; t0>=0, t1<=1 by construction
#define EDGE(PX,PY,QX,QY,HPS) { \
        const float Px = (PX), Py = (PY); \
        const float Dx = (QX) - Px, Dy = (QY) - Py; \
        float t0a = 0.f, t1a = 1.f, t0b = 0.f, t1b = 1.f; \
        HPS \
        float dt = fminf(t1a, t1b) - fmaxf(t0a, t0b); \
        float cpd = Px*Dy - Py*Dx; \
        inter2 += (dt > 0.f) ? dt*cpd : 0.f; }

    EDGE(ax0,ay0,ax1,ay1,HPB) EDGE(ax1,ay1,ax2,ay2,HPB)
    EDGE(ax2,ay2,ax3,ay3,HPB) EDGE(ax3,ay3,ax4,ay4,HPB)
    EDGE(ax4,ay4,ax5,ay5,HPB) EDGE(ax5,ay5,ax6,ay6,HPB)
    EDGE(ax6,ay6,ax7,ay7,HPB) EDGE(ax7,ay7,ax0,ay0,HPB)
    EDGE(bx0,by0,bx1,by1,HPA) EDGE(bx1,by1,bx2,by2,HPA)
    EDGE(bx2,by2,bx3,by3,HPA) EDGE(bx3,by3,bx4,by4,HPA)
    EDGE(bx4,by4,bx5,by5,HPA) EDGE(bx5,by5,bx6,by6,HPA)
    EDGE(bx6,by6,bx7,by7,HPA) EDGE(bx7,by7,bx0,by0,HPA)

    float inter = fmaxf(0.5f * inter2, 0.f);
    float uni = area_a + area_b - inter;
    float iou = __fdividef(inter, uni);

    // ---- Hull start: serial min by (y,x) over all 16 ----
    float stx = ax0, sty = ay0;
#define UPD(PX,PY) { \
        bool bs = ((PY) < sty) || (((PY) == sty) && ((PX) < stx)); \
        stx = bs ? (PX) : stx; sty = bs ? (PY) : sty; }
    UPD(ax1,ay1) UPD(ax2,ay2) UPD(ax3,ay3) UPD(ax4,ay4)
    UPD(ax5,ay5) UPD(ax6,ay6) UPD(ax7,ay7)
    UPD(bx0,by0) UPD(bx1,by1) UPD(bx2,by2) UPD(bx3,by3)
    UPD(bx4,by4) UPD(bx5,by5) UPD(bx6,by6) UPD(bx7,by7)

    // ---- Jarvis march: two independent 8-point chains + one merge ----
    // Both chains seeded with -din (loses to every real candidate; the
    // self-point gives cr==0, never taken). Merge tie keeps the A-side ==
    // serial A-first scan order. nx/ny select exact original coords so the
    // done-equality matches the reference's termination (r9/r10-validated).
    float cxv = stx, cyv = sty, accH = 0.f;
    float pdx = 1.f, pdy = 0.f;          // reference's initial heading (1,0)
    bool done = false;
    for (int it = 0; it < 16; ++it) {
        float cdxa = -pdx, cdya = -pdy;
        float nxa = cxv, nya = cyv;
        float cdxb = -pdx, cdyb = -pdy;
        float nxb = cxv, nyb = cyv;
#define SCANV(CDX,CDY,NX,NY,PX,PY) { \
            float vx = (PX) - cxv, vy = (PY) - cyv; \
            float cr = CDX*vy - CDY*vx; \
            bool take = cr < 0.f; \
            NX = take ? (PX) : NX;  NY = take ? (PY) : NY; \
            CDX = take ? vx : CDX;  CDY = take ? vy : CDY; }
        SCANV(cdxa,cdya,nxa,nya, ax0,ay0) SCANV(cdxa,cdya,nxa,nya, ax1,ay1)
        SCANV(cdxa,cdya,nxa,nya, ax2,ay2) SCANV(cdxa,cdya,nxa,nya, ax3,ay3)
        SCANV(cdxa,cdya,nxa,nya, ax4,ay4) SCANV(cdxa,cdya,nxa,nya, ax5,ay5)
        SCANV(cdxa,cdya,nxa,nya, ax6,ay6) SCANV(cdxa,cdya,nxa,nya, ax7,ay7)
        SCANV(cdxb,cdyb,nxb,nyb, bx0,by0) SCANV(cdxb,cdyb,nxb,nyb, bx1,by1)
        SCANV(cdxb,cdyb,nxb,nyb, bx2,by2) SCANV(cdxb,cdyb,nxb,nyb, bx3,by3)
        SCANV(cdxb,cdyb,nxb,nyb, bx4,by4) SCANV(cdxb,cdyb,nxb,nyb, bx5,by5)
        SCANV(cdxb,cdyb,nxb,nyb, bx6,by6) SCANV(cdxb,cdyb,nxb,nyb, bx7,by7)
        // merge: B wins iff strictly more clockwise than A's candidate
        float crm = cdxa*cdyb - cdya*cdxb;
        bool tkb = crm < 0.f;
        float nx = tkb ? nxb : nxa;
        float ny = tkb ? nyb : nya;
        accH += done ? 0.f : (cxv*ny - cyv*nx);
        done = done || (nx == stx && ny == sty);
        pdx = nx - cxv; pdy = ny - cyv;   // == selected candidate direction
        cxv = nx; cyv = ny;
        if (__all(done)) break;
    }
    float ch = 0.5f * accH;

    float val = iou - __fdividef(ch - uni, ch);
    float v = live ? val : 0.f;

    // ---- reduction: wave shuffle -> LDS(16B) -> global double atomic ----
    #pragma unroll
    for (int off = 32; off > 0; off >>= 1) v += __shfl_down(v, off);
    __shared__ float wsum[4];
    int lane = t & 63, wid = t >> 6;
    if (lane == 0) wsum[wid] = v;
    __syncthreads();
    if (t == 0) {
        double bsum = (double)wsum[0] + (double)wsum[1]
                    + (double)wsum[2] + (double)wsum[3];
        atomicAdd(acc, bsum);
        __threadfence();
        unsigned int old = atomicAdd(cnt, 1u);
        if (old == (unsigned int)(nblocks - 1)) {
            double total = atomicAdd(acc, 0.0);   // read after all adds visible
            out[0] = (float)(total / (double)nbatch);
        }
    }
}

extern "C" void kernel_launch(void* const* d_in, const int* in_sizes, int n_in,
                              void* d_out, int out_size, void* d_ws, size_t ws_size,
                              hipStream_t stream) {
    const float* a = (const float*)d_in[0];
    const float* b = (const float*)d_in[1];
    float* out = (float*)d_out;
    int nbatch = in_sizes[0] / 16;
    int nblocks = (nbatch + TPB - 1) / TPB;
    double* acc = (double*)d_ws;                          // [0,8): double sum
    unsigned int* cnt = (unsigned int*)((char*)d_ws + 8); // [8,12): counter
    hipMemsetAsync(d_ws, 0, 16, stream);
    ciou_fused<<<nblocks, TPB, 0, stream>>>(a, b, out, acc, cnt, nbatch, nblocks);
}

// Round 15
// 110.551 us; speedup vs baseline: 1.0330x; 1.0330x over previous
//
#include <hip/hip_runtime.h>

#define TPB 256

// Fused CIoU, 1 thread/element — r13 hot path verbatim (55.6us, clean
// 116-VGPR allocation) + STRIPED reduction epilogue:
//   r11/r13/r14 plateau at 55±2us across three different instruction mixes
//   (both clip- and march-chain halvings were neutral) -> limiter is
//   mix-independent. Suspect: ~1024 device-scope f64 atomicAdds bursting
//   onto ONE cache line (plus the counter line) -> serialized cross-XCD
//   line ping-pong tail. Fix: 64 stripes on separate 128B lines; elected
//   last block reads stripes in parallel across wave-0 lanes.
// Codegen law (r3..r14): serial chains + block-local temps, TPB=256,
// no arrays, no in-loop shuffles, no cross-block hoists.
__global__ __launch_bounds__(TPB, 2) void ciou_fused(
    const float* __restrict__ A,
    const float* __restrict__ Bq,
    float* __restrict__ out,
    double* __restrict__ acc,
    unsigned int* __restrict__ cnt,
    int nbatch, int nblocks)
{
    const int t = threadIdx.x;
    const int i0 = blockIdx.x * TPB + t;
    const bool live = (i0 < nbatch);
    const int i = live ? i0 : (nbatch - 1);

    float ax0,ax1,ax2,ax3,ax4,ax5,ax6,ax7;
    float ay0,ay1,ay2,ay3,ay4,ay5,ay6,ay7;
    float bx0,bx1,bx2,bx3,bx4,bx5,bx6,bx7;
    float by0,by1,by2,by3,by4,by5,by6,by7;
    {
        const float4* pa = (const float4*)(A + (size_t)i * 16);
        const float4* pb = (const float4*)(Bq + (size_t)i * 16);
        float4 q;
        q = pa[0]; ax0=q.x; ay0=q.y; ax1=q.z; ay1=q.w;
        q = pa[1]; ax2=q.x; ay2=q.y; ax3=q.z; ay3=q.w;
        q = pa[2]; ax4=q.x; ay4=q.y; ax5=q.z; ay5=q.w;
        q = pa[3]; ax6=q.x; ay6=q.y; ax7=q.z; ay7=q.w;
        q = pb[0]; bx0=q.x; by0=q.y; bx1=q.z; by1=q.w;
        q = pb[1]; bx2=q.x; by2=q.y; bx3=q.z; by3=q.w;
        q = pb[2]; bx4=q.x; by4=q.y; bx5=q.z; by5=q.w;
        q = pb[3]; bx6=q.x; by6=q.y; bx7=q.z; by7=q.w;
    }

    // Shoelace areas (input vertex order is CCW; sort_poly = rotation).
    float area_a = 0.5f * ((ax0*ay1-ay0*ax1) + (ax1*ay2-ay1*ax2)
                         + (ax2*ay3-ay2*ax3) + (ax3*ay4-ay3*ax4)
                         + (ax4*ay5-ay4*ax5) + (ax5*ay6-ay5*ax6)
                         + (ax6*ay7-ay6*ax7) + (ax7*ay0-ay7*ax0));
    float area_b = 0.5f * ((bx0*by1-by0*bx1) + (bx1*by2-by1*bx2)
                         + (bx2*by3-by2*bx3) + (bx3*by4-by3*bx4)
                         + (bx4*by5-by4*bx5) + (bx5*by6-by5*bx6)
                         + (bx6*by7-by6*bx7) + (bx7*by0-by7*bx0));

    // ---- Intersection: Green's theorem over clipped edges ----
    float inter2 = 0.f;

    // inside Q iff cross(E_Q, p - V_Q) >= 0; along edge: aa + t*bb >= 0.
    // Branchless: h = bb*1e38 (+big if bb>0, -big if bb<0); IEEE min/max
    // absorb the unused arm. bb==0 (parallel) is measure-zero (r10+ absmax 0).
#define HP(T0,T1,QX0,QY0,QX1,QY1) { \
        float ex = (QX1)-(QX0), ey = (QY1)-(QY0); \
        float aa = ex*(Py-(QY0)) - ey*(Px-(QX0)); \
        float bb = ex*Dy - ey*Dx; \
        float tc = __fdividef(-aa, bb); \
        float h = bb * 1e38f; \
        T0 = fmaxf(T0, fminf(tc, h)); \
        T1 = fminf(T1, fmaxf(tc, h)); }

#define HPB HP(t0a,t1a,bx0,by0,bx1,by1) HP(t0b,t1b,bx1,by1,bx2,by2) \
            HP(t0a,t1a,bx2,by2,bx3,by3) HP(t0b,t1b,bx3,by3,bx4,by4) \
            HP(t0a,t1a,bx4,by4,bx5,by5) HP(t0b,t1b,bx5,by5,bx6,by6) \
            HP(t0a,t1a,bx6,by6,bx7,by7) HP(t0b,t1b,bx7,by7,bx0,by0)
#define HPA HP(t0a,t1a,ax0,ay0,ax1,ay1) HP(t0b,t1b,ax1,ay1,ax2,ay2) \
            HP(t0a,t1a,ax2,ay2,ax3,ay3) HP(t0b,t1b,ax3,ay3,ax4,ay4) \
            HP(t0a,t1a,ax4,ay4,ax5,ay5) HP(t0b,t1b,ax5,ay5,ax6,ay6) \
            HP(t0a,t1a,ax6,ay6,ax7,ay7) HP(t0b,t1b,ax7,ay7,ax0,ay0)

    // cross(P(t0),P(t1)) = (t1-t0)*cross(P,D) ; t0>=0, t1<=1 by construction
#define EDGE(PX,PY,QX,QY,HPS) { \
        const float Px = (PX), Py = (PY); \
        const float Dx = (QX) - Px, Dy = (QY) - Py; \
        float t0a = 0.f, t1a = 1.f, t0b = 0.f, t1b = 1.f; \
        HPS \
        float dt = fminf(t1a, t1b) - fmaxf(t0a, t0b); \
        float cpd = Px*Dy - Py*Dx; \
        inter2 += (dt > 0.f) ? dt*cpd : 0.f; }

    EDGE(ax0,ay0,ax1,ay1,HPB) EDGE(ax1,ay1,ax2,ay2,HPB)
    EDGE(ax2,ay2,ax3,ay3,HPB) EDGE(ax3,ay3,ax4,ay4,HPB)
    EDGE(ax4,ay4,ax5,ay5,HPB) EDGE(ax5,ay5,ax6,ay6,HPB)
    EDGE(ax6,ay6,ax7,ay7,HPB) EDGE(ax7,ay7,ax0,ay0,HPB)
    EDGE(bx0,by0,bx1,by1,HPA) EDGE(bx1,by1,bx2,by2,HPA)
    EDGE(bx2,by2,bx3,by3,HPA) EDGE(bx3,by3,bx4,by4,HPA)
    EDGE(bx4,by4,bx5,by5,HPA) EDGE(bx5,by5,bx6,by6,HPA)
    EDGE(bx6,by6,bx7,by7,HPA) EDGE(bx7,by7,bx0,by0,HPA)

    float inter = fmaxf(0.5f * inter2, 0.f);
    float uni = area_a + area_b - inter;
    float iou = __fdividef(inter, uni);

    // ---- Hull start: serial min by (y,x) over all 16 ----
    float stx = ax0, sty = ay0;
#define UPD(PX,PY) { \
        bool bs = ((PY) < sty) || (((PY) == sty) && ((PX) < stx)); \
        stx = bs ? (PX) : stx; sty = bs ? (PY) : sty; }
    UPD(ax1,ay1) UPD(ax2,ay2) UPD(ax3,ay3) UPD(ax4,ay4)
    UPD(ax5,ay5) UPD(ax6,ay6) UPD(ax7,ay7)
    UPD(bx0,by0) UPD(bx1,by1) UPD(bx2,by2) UPD(bx3,by3)
    UPD(bx4,by4) UPD(bx5,by5) UPD(bx6,by6) UPD(bx7,by7)

    // ---- Jarvis march, candidate seeded with negated incoming direction ----
    // (r9/r10-validated: every true candidate beats -din via cross<0; the
    // self-point gives cr==0, never taken; nx/ny select exact original
    // coords so the done-equality matches the reference's termination.)
    float cxv = stx, cyv = sty, accH = 0.f;
    float pdx = 1.f, pdy = 0.f;          // reference's initial heading (1,0)
    bool done = false;
    for (int it = 0; it < 16; ++it) {
        float cdx = -pdx, cdy = -pdy;
        float nx = cxv, ny = cyv;
#define SCAN(PX,PY) { \
            float vx = (PX) - cxv, vy = (PY) - cyv; \
            float cr = cdx*vy - cdy*vx; \
            bool take = cr < 0.f; \
            nx = take ? (PX) : nx;  ny = take ? (PY) : ny; \
            cdx = take ? vx : cdx;  cdy = take ? vy : cdy; }
        SCAN(ax0,ay0) SCAN(ax1,ay1) SCAN(ax2,ay2) SCAN(ax3,ay3)
        SCAN(ax4,ay4) SCAN(ax5,ay5) SCAN(ax6,ay6) SCAN(ax7,ay7)
        SCAN(bx0,by0) SCAN(bx1,by1) SCAN(bx2,by2) SCAN(bx3,by3)
        SCAN(bx4,by4) SCAN(bx5,by5) SCAN(bx6,by6) SCAN(bx7,by7)
        accH += done ? 0.f : (cxv*ny - cyv*nx);
        done = done || (nx == stx && ny == sty);
        pdx = cdx; pdy = cdy;
        cxv = nx; cyv = ny;
        if (__all(done)) break;
    }
    float ch = 0.5f * accH;

    float val = iou - __fdividef(ch - uni, ch);
    float v = live ? val : 0.f;

    // ---- reduction: wave shuffle -> LDS(16B) -> STRIPED global atomics ----
    #pragma unroll
    for (int off = 32; off > 0; off >>= 1) v += __shfl_down(v, off);
    __shared__ float wsum[4];
    __shared__ int elected;
    int lane = t & 63, wid = t >> 6;
    if (lane == 0) wsum[wid] = v;
    __syncthreads();
    if (t == 0) {
        double bsum = (double)wsum[0] + (double)wsum[1]
                    + (double)wsum[2] + (double)wsum[3];
        // 64 stripes, each on its own 128B line -> 64-way parallel atomics
        atomicAdd(acc + ((blockIdx.x & 63) << 4), bsum);
        __threadfence();
        unsigned int old = atomicAdd(cnt, 1u);
        elected = (old == (unsigned int)(nblocks - 1)) ? 1 : 0;
    }
    __syncthreads();
    if (elected) {
        if (t < 64) {   // wave 0 only: parallel stripe read + shuffle reduce
            double tv = atomicAdd(acc + (t << 4), 0.0);  // atomic read
            #pragma unroll
            for (int off = 32; off > 0; off >>= 1)
                tv += __shfl_down(tv, off);
            if (t == 0) out[0] = (float)(tv / (double)nbatch);
        }
    }
}

extern "C" void kernel_launch(void* const* d_in, const int* in_sizes, int n_in,
                              void* d_out, int out_size, void* d_ws, size_t ws_size,
                              hipStream_t stream) {
    const float* a = (const float*)d_in[0];
    const float* b = (const float*)d_in[1];
    float* out = (float*)d_out;
    int nbatch = in_sizes[0] / 16;
    int nblocks = (nbatch + TPB - 1) / TPB;
    double* acc = (double*)d_ws;                // 64 stripes * 16 doubles = 8KB
    unsigned int* cnt = (unsigned int*)((char*)d_ws + 8192);
    hipMemsetAsync(d_ws, 0, 8192 + 16, stream); // zero stripes + counter
    ciou_fused<<<nblocks, TPB, 0, stream>>>(a, b, out, acc, cnt, nbatch, nblocks);
}

// Round 16
// 103.467 us; speedup vs baseline: 1.1037x; 1.0685x over previous
//
#include <hip/hip_runtime.h>

#define TPB 256

// Fused CIoU, 1 thread/element — r13 hot path verbatim (best clean kernel,
// 116 VGPR) with a WAIT-FREE epilogue:
//   r15 showed the completion protocol (device-scope atomics + barrier)
//   serializes block retirement (identical busy cycles, worse overlap).
//   Fix: plain per-block partial store (no atomics, no counter, no second
//   barrier) + tiny finalize kernel. No workspace memset needed.
// Codegen law (r3..r15): serial chains + block-local temps, TPB=256,
// no arrays, no in-loop shuffles, no cross-block hoists.
__global__ __launch_bounds__(TPB, 2) void ciou_main(
    const float* __restrict__ A,
    const float* __restrict__ Bq,
    double* __restrict__ partial,
    int nbatch)
{
    const int t = threadIdx.x;
    const int i0 = blockIdx.x * TPB + t;
    const bool live = (i0 < nbatch);
    const int i = live ? i0 : (nbatch - 1);

    float ax0,ax1,ax2,ax3,ax4,ax5,ax6,ax7;
    float ay0,ay1,ay2,ay3,ay4,ay5,ay6,ay7;
    float bx0,bx1,bx2,bx3,bx4,bx5,bx6,bx7;
    float by0,by1,by2,by3,by4,by5,by6,by7;
    {
        const float4* pa = (const float4*)(A + (size_t)i * 16);
        const float4* pb = (const float4*)(Bq + (size_t)i * 16);
        float4 q;
        q = pa[0]; ax0=q.x; ay0=q.y; ax1=q.z; ay1=q.w;
        q = pa[1]; ax2=q.x; ay2=q.y; ax3=q.z; ay3=q.w;
        q = pa[2]; ax4=q.x; ay4=q.y; ax5=q.z; ay5=q.w;
        q = pa[3]; ax6=q.x; ay6=q.y; ax7=q.z; ay7=q.w;
        q = pb[0]; bx0=q.x; by0=q.y; bx1=q.z; by1=q.w;
        q = pb[1]; bx2=q.x; by2=q.y; bx3=q.z; by3=q.w;
        q = pb[2]; bx4=q.x; by4=q.y; bx5=q.z; by5=q.w;
        q = pb[3]; bx6=q.x; by6=q.y; bx7=q.z; by7=q.w;
    }

    // Shoelace areas (input vertex order is CCW; sort_poly = rotation).
    float area_a = 0.5f * ((ax0*ay1-ay0*ax1) + (ax1*ay2-ay1*ax2)
                         + (ax2*ay3-ay2*ax3) + (ax3*ay4-ay3*ax4)
                         + (ax4*ay5-ay4*ax5) + (ax5*ay6-ay5*ax6)
                         + (ax6*ay7-ay6*ax7) + (ax7*ay0-ay7*ax0));
    float area_b = 0.5f * ((bx0*by1-by0*bx1) + (bx1*by2-by1*bx2)
                         + (bx2*by3-by2*bx3) + (bx3*by4-by3*bx4)
                         + (bx4*by5-by4*bx5) + (bx5*by6-by5*bx6)
                         + (bx6*by7-by6*bx7) + (bx7*by0-by7*bx0));

    // ---- Intersection: Green's theorem over clipped edges ----
    float inter2 = 0.f;

    // inside Q iff cross(E_Q, p - V_Q) >= 0; along edge: aa + t*bb >= 0.
    // Branchless: h = bb*1e38 (+big if bb>0, -big if bb<0); IEEE min/max
    // absorb the unused arm. bb==0 (parallel) is measure-zero (r10+ absmax 0).
#define HP(T0,T1,QX0,QY0,QX1,QY1) { \
        float ex = (QX1)-(QX0), ey = (QY1)-(QY0); \
        float aa = ex*(Py-(QY0)) - ey*(Px-(QX0)); \
        float bb = ex*Dy - ey*Dx; \
        float tc = __fdividef(-aa, bb); \
        float h = bb * 1e38f; \
        T0 = fmaxf(T0, fminf(tc, h)); \
        T1 = fminf(T1, fmaxf(tc, h)); }

#define HPB HP(t0a,t1a,bx0,by0,bx1,by1) HP(t0b,t1b,bx1,by1,bx2,by2) \
            HP(t0a,t1a,bx2,by2,bx3,by3) HP(t0b,t1b,bx3,by3,bx4,by4) \
            HP(t0a,t1a,bx4,by4,bx5,by5) HP(t0b,t1b,bx5,by5,bx6,by6) \
            HP(t0a,t1a,bx6,by6,bx7,by7) HP(t0b,t1b,bx7,by7,bx0,by0)
#define HPA HP(t0a,t1a,ax0,ay0,ax1,ay1) HP(t0b,t1b,ax1,ay1,ax2,ay2) \
            HP(t0a,t1a,ax2,ay2,ax3,ay3) HP(t0b,t1b,ax3,ay3,ax4,ay4) \
            HP(t0a,t1a,ax4,ay4,ax5,ay5) HP(t0b,t1b,ax5,ay5,ax6,ay6) \
            HP(t0a,t1a,ax6,ay6,ax7,ay7) HP(t0b,t1b,ax7,ay7,ax0,ay0)

    // cross(P(t0),P(t1)) = (t1-t0)*cross(P,D) ; t0>=0, t1<=1 by construction
#define EDGE(PX,PY,QX,QY,HPS) { \
        const float Px = (PX), Py = (PY); \
        const float Dx = (QX) - Px, Dy = (QY) - Py; \
        float t0a = 0.f, t1a = 1.f, t0b = 0.f, t1b = 1.f; \
        HPS \
        float dt = fminf(t1a, t1b) - fmaxf(t0a, t0b); \
        float cpd = Px*Dy - Py*Dx; \
        inter2 += (dt > 0.f) ? dt*cpd : 0.f; }

    EDGE(ax0,ay0,ax1,ay1,HPB) EDGE(ax1,ay1,ax2,ay2,HPB)
    EDGE(ax2,ay2,ax3,ay3,HPB) EDGE(ax3,ay3,ax4,ay4,HPB)
    EDGE(ax4,ay4,ax5,ay5,HPB) EDGE(ax5,ay5,ax6,ay6,HPB)
    EDGE(ax6,ay6,ax7,ay7,HPB) EDGE(ax7,ay7,ax0,ay0,HPB)
    EDGE(bx0,by0,bx1,by1,HPA) EDGE(bx1,by1,bx2,by2,HPA)
    EDGE(bx2,by2,bx3,by3,HPA) EDGE(bx3,by3,bx4,by4,HPA)
    EDGE(bx4,by4,bx5,by5,HPA) EDGE(bx5,by5,bx6,by6,HPA)
    EDGE(bx6,by6,bx7,by7,HPA) EDGE(bx7,by7,bx0,by0,HPA)

    float inter = fmaxf(0.5f * inter2, 0.f);
    float uni = area_a + area_b - inter;
    float iou = __fdividef(inter, uni);

    // ---- Hull start: serial min by (y,x) over all 16 ----
    float stx = ax0, sty = ay0;
#define UPD(PX,PY) { \
        bool bs = ((PY) < sty) || (((PY) == sty) && ((PX) < stx)); \
        stx = bs ? (PX) : stx; sty = bs ? (PY) : sty; }
    UPD(ax1,ay1) UPD(ax2,ay2) UPD(ax3,ay3) UPD(ax4,ay4)
    UPD(ax5,ay5) UPD(ax6,ay6) UPD(ax7,ay7)
    UPD(bx0,by0) UPD(bx1,by1) UPD(bx2,by2) UPD(bx3,by3)
    UPD(bx4,by4) UPD(bx5,by5) UPD(bx6,by6) UPD(bx7,by7)

    // ---- Jarvis march, candidate seeded with negated incoming direction ----
    // (r9/r10-validated: every true candidate beats -din via cross<0; the
    // self-point gives cr==0, never taken; nx/ny select exact original
    // coords so the done-equality matches the reference's termination.)
    float cxv = stx, cyv = sty, accH = 0.f;
    float pdx = 1.f, pdy = 0.f;          // reference's initial heading (1,0)
    bool done = false;
    for (int it = 0; it < 16; ++it) {
        float cdx = -pdx, cdy = -pdy;
        float nx = cxv, ny = cyv;
#define SCAN(PX,PY) { \
            float vx = (PX) - cxv, vy = (PY) - cyv; \
            float cr = cdx*vy - cdy*vx; \
            bool take = cr < 0.f; \
            nx = take ? (PX) : nx;  ny = take ? (PY) : ny; \
            cdx = take ? vx : cdx;  cdy = take ? vy : cdy; }
        SCAN(ax0,ay0) SCAN(ax1,ay1) SCAN(ax2,ay2) SCAN(ax3,ay3)
        SCAN(ax4,ay4) SCAN(ax5,ay5) SCAN(ax6,ay6) SCAN(ax7,ay7)
        SCAN(bx0,by0) SCAN(bx1,by1) SCAN(bx2,by2) SCAN(bx3,by3)
        SCAN(bx4,by4) SCAN(bx5,by5) SCAN(bx6,by6) SCAN(bx7,by7)
        accH += done ? 0.f : (cxv*ny - cyv*nx);
        done = done || (nx == stx && ny == sty);
        pdx = cdx; pdy = cdy;
        cxv = nx; cyv = ny;
        if (__all(done)) break;
    }
    float ch = 0.5f * accH;

    float val = iou - __fdividef(ch - uni, ch);
    float v = live ? val : 0.f;

    // ---- epilogue: shuffle -> LDS(16B) -> ONE plain store. Zero waits. ----
    #pragma unroll
    for (int off = 32; off > 0; off >>= 1) v += __shfl_down(v, off);
    __shared__ float wsum[4];
    int lane = t & 63, wid = t >> 6;
    if (lane == 0) wsum[wid] = v;
    __syncthreads();
    if (t == 0) {
        partial[blockIdx.x] = (double)wsum[0] + (double)wsum[1]
                            + (double)wsum[2] + (double)wsum[3];
    }
}

__global__ __launch_bounds__(256) void ciou_finalize(
    const double* __restrict__ partial, float* __restrict__ out,
    int nparts, int nbatch)
{
    double v = 0.0;
    for (int j = threadIdx.x; j < nparts; j += 256) v += partial[j];
    #pragma unroll
    for (int off = 32; off > 0; off >>= 1) v += __shfl_down(v, off);
    __shared__ double s[4];
    int lane = threadIdx.x & 63, wid = threadIdx.x >> 6;
    if (lane == 0) s[wid] = v;
    __syncthreads();
    if (threadIdx.x == 0)
        out[0] = (float)((s[0] + s[1] + s[2] + s[3]) / (double)nbatch);
}

extern "C" void kernel_launch(void* const* d_in, const int* in_sizes, int n_in,
                              void* d_out, int out_size, void* d_ws, size_t ws_size,
                              hipStream_t stream) {
    const float* a = (const float*)d_in[0];
    const float* b = (const float*)d_in[1];
    float* out = (float*)d_out;
    int nbatch = in_sizes[0] / 16;
    int nblocks = (nbatch + TPB - 1) / TPB;
    double* partial = (double*)d_ws;   // fully overwritten each call; no memset
    ciou_main<<<nblocks, TPB, 0, stream>>>(a, b, partial, nbatch);
    ciou_finalize<<<1, 256, 0, stream>>>(partial, out, nblocks, nbatch);
}

// Round 17
// 100.604 us; speedup vs baseline: 1.1352x; 1.0285x over previous
//
#include <hip/hip_runtime.h>

#define TPB 256

// Fused CIoU, 1 thread/element — r16 structure (best: 103.5us bench) with
// two zero-risk local trims:
//   1. EDGE: inter2 += fmaxf(dt,0)*cpd  (dt<=0 -> exact 0; replaces select).
//   2. live-guard collapsed when grid divides exactly (262144 = 1024*256);
//      generic tail path kept for safety via 'tail' flag.
// Epilogue: wait-free per-block partial store + tiny finalize kernel (r16).
// Codegen law (r3..r15): serial chains + block-local temps, TPB=256,
// no arrays, no in-loop shuffles, no cross-block hoists.
__global__ __launch_bounds__(TPB, 2) void ciou_main(
    const float* __restrict__ A,
    const float* __restrict__ Bq,
    double* __restrict__ partial,
    int nbatch, int tail)
{
    const int t = threadIdx.x;
    const int i0 = blockIdx.x * TPB + t;
    const bool live = !tail || (i0 < nbatch);
    const int i = live ? i0 : (nbatch - 1);

    float ax0,ax1,ax2,ax3,ax4,ax5,ax6,ax7;
    float ay0,ay1,ay2,ay3,ay4,ay5,ay6,ay7;
    float bx0,bx1,bx2,bx3,bx4,bx5,bx6,bx7;
    float by0,by1,by2,by3,by4,by5,by6,by7;
    {
        const float4* pa = (const float4*)(A + (size_t)i * 16);
        const float4* pb = (const float4*)(Bq + (size_t)i * 16);
        float4 q;
        q = pa[0]; ax0=q.x; ay0=q.y; ax1=q.z; ay1=q.w;
        q = pa[1]; ax2=q.x; ay2=q.y; ax3=q.z; ay3=q.w;
        q = pa[2]; ax4=q.x; ay4=q.y; ax5=q.z; ay5=q.w;
        q = pa[3]; ax6=q.x; ay6=q.y; ax7=q.z; ay7=q.w;
        q = pb[0]; bx0=q.x; by0=q.y; bx1=q.z; by1=q.w;
        q = pb[1]; bx2=q.x; by2=q.y; bx3=q.z; by3=q.w;
        q = pb[2]; bx4=q.x; by4=q.y; bx5=q.z; by5=q.w;
        q = pb[3]; bx6=q.x; by6=q.y; bx7=q.z; by7=q.w;
    }

    // Shoelace areas (input vertex order is CCW; sort_poly = rotation).
    float area_a = 0.5f * ((ax0*ay1-ay0*ax1) + (ax1*ay2-ay1*ax2)
                         + (ax2*ay3-ay2*ax3) + (ax3*ay4-ay3*ax4)
                         + (ax4*ay5-ay4*ax5) + (ax5*ay6-ay5*ax6)
                         + (ax6*ay7-ay6*ax7) + (ax7*ay0-ay7*ax0));
    float area_b = 0.5f * ((bx0*by1-by0*bx1) + (bx1*by2-by1*bx2)
                         + (bx2*by3-by2*bx3) + (bx3*by4-by3*bx4)
                         + (bx4*by5-by4*bx5) + (bx5*by6-by5*bx6)
                         + (bx6*by7-by6*bx7) + (bx7*by0-by7*bx0));

    // ---- Intersection: Green's theorem over clipped edges ----
    float inter2 = 0.f;

    // inside Q iff cross(E_Q, p - V_Q) >= 0; along edge: aa + t*bb >= 0.
    // Branchless: h = bb*1e38 (+big if bb>0, -big if bb<0); IEEE min/max
    // absorb the unused arm. bb==0 (parallel) is measure-zero (r10+ absmax 0).
#define HP(T0,T1,QX0,QY0,QX1,QY1) { \
        float ex = (QX1)-(QX0), ey = (QY1)-(QY0); \
        float aa = ex*(Py-(QY0)) - ey*(Px-(QX0)); \
        float bb = ex*Dy - ey*Dx; \
        float tc = __fdividef(-aa, bb); \
        float h = bb * 1e38f; \
        T0 = fmaxf(T0, fminf(tc, h)); \
        T1 = fminf(T1, fmaxf(tc, h)); }

#define HPB HP(t0a,t1a,bx0,by0,bx1,by1) HP(t0b,t1b,bx1,by1,bx2,by2) \
            HP(t0a,t1a,bx2,by2,bx3,by3) HP(t0b,t1b,bx3,by3,bx4,by4) \
            HP(t0a,t1a,bx4,by4,bx5,by5) HP(t0b,t1b,bx5,by5,bx6,by6) \
            HP(t0a,t1a,bx6,by6,bx7,by7) HP(t0b,t1b,bx7,by7,bx0,by0)
#define HPA HP(t0a,t1a,ax0,ay0,ax1,ay1) HP(t0b,t1b,ax1,ay1,ax2,ay2) \
            HP(t0a,t1a,ax2,ay2,ax3,ay3) HP(t0b,t1b,ax3,ay3,ax4,ay4) \
            HP(t0a,t1a,ax4,ay4,ax5,ay5) HP(t0b,t1b,ax5,ay5,ax6,ay6) \
            HP(t0a,t1a,ax6,ay6,ax7,ay7) HP(t0b,t1b,ax7,ay7,ax0,ay0)

    // cross(P(t0),P(t1)) = (t1-t0)*cross(P,D); dt<=0 -> fmax gives exact 0.
#define EDGE(PX,PY,QX,QY,HPS) { \
        const float Px = (PX), Py = (PY); \
        const float Dx = (QX) - Px, Dy = (QY) - Py; \
        float t0a = 0.f, t1a = 1.f, t0b = 0.f, t1b = 1.f; \
        HPS \
        float dt = fminf(t1a, t1b) - fmaxf(t0a, t0b); \
        float cpd = Px*Dy - Py*Dx; \
        inter2 += fmaxf(dt, 0.f) * cpd; }

    EDGE(ax0,ay0,ax1,ay1,HPB) EDGE(ax1,ay1,ax2,ay2,HPB)
    EDGE(ax2,ay2,ax3,ay3,HPB) EDGE(ax3,ay3,ax4,ay4,HPB)
    EDGE(ax4,ay4,ax5,ay5,HPB) EDGE(ax5,ay5,ax6,ay6,HPB)
    EDGE(ax6,ay6,ax7,ay7,HPB) EDGE(ax7,ay7,ax0,ay0,HPB)
    EDGE(bx0,by0,bx1,by1,HPA) EDGE(bx1,by1,bx2,by2,HPA)
    EDGE(bx2,by2,bx3,by3,HPA) EDGE(bx3,by3,bx4,by4,HPA)
    EDGE(bx4,by4,bx5,by5,HPA) EDGE(bx5,by5,bx6,by6,HPA)
    EDGE(bx6,by6,bx7,by7,HPA) EDGE(bx7,by7,bx0,by0,HPA)

    float inter = fmaxf(0.5f * inter2, 0.f);
    float uni = area_a + area_b - inter;
    float iou = __fdividef(inter, uni);

    // ---- Hull start: serial min by (y,x) over all 16 ----
    float stx = ax0, sty = ay0;
#define UPD(PX,PY) { \
        bool bs = ((PY) < sty) || (((PY) == sty) && ((PX) < stx)); \
        stx = bs ? (PX) : stx; sty = bs ? (PY) : sty; }
    UPD(ax1,ay1) UPD(ax2,ay2) UPD(ax3,ay3) UPD(ax4,ay4)
    UPD(ax5,ay5) UPD(ax6,ay6) UPD(ax7,ay7)
    UPD(bx0,by0) UPD(bx1,by1) UPD(bx2,by2) UPD(bx3,by3)
    UPD(bx4,by4) UPD(bx5,by5) UPD(bx6,by6) UPD(bx7,by7)

    // ---- Jarvis march, candidate seeded with negated incoming direction ----
    // (r9/r10-validated: every true candidate beats -din via cross<0; the
    // self-point gives cr==0, never taken; nx/ny select exact original
    // coords so the done-equality matches the reference's termination.)
    float cxv = stx, cyv = sty, accH = 0.f;
    float pdx = 1.f, pdy = 0.f;          // reference's initial heading (1,0)
    bool done = false;
    for (int it = 0; it < 16; ++it) {
        float cdx = -pdx, cdy = -pdy;
        float nx = cxv, ny = cyv;
#define SCAN(PX,PY) { \
            float vx = (PX) - cxv, vy = (PY) - cyv; \
            float cr = cdx*vy - cdy*vx; \
            bool take = cr < 0.f; \
            nx = take ? (PX) : nx;  ny = take ? (PY) : ny; \
            cdx = take ? vx : cdx;  cdy = take ? vy : cdy; }
        SCAN(ax0,ay0) SCAN(ax1,ay1) SCAN(ax2,ay2) SCAN(ax3,ay3)
        SCAN(ax4,ay4) SCAN(ax5,ay5) SCAN(ax6,ay6) SCAN(ax7,ay7)
        SCAN(bx0,by0) SCAN(bx1,by1) SCAN(bx2,by2) SCAN(bx3,by3)
        SCAN(bx4,by4) SCAN(bx5,by5) SCAN(bx6,by6) SCAN(bx7,by7)
        accH += done ? 0.f : (cxv*ny - cyv*nx);
        done = done || (nx == stx && ny == sty);
        pdx = cdx; pdy = cdy;
        cxv = nx; cyv = ny;
        if (__all(done)) break;
    }
    float ch = 0.5f * accH;

    float val = iou - __fdividef(ch - uni, ch);
    float v = live ? val : 0.f;

    // ---- epilogue: shuffle -> LDS(16B) -> ONE plain store. Zero waits. ----
    #pragma unroll
    for (int off = 32; off > 0; off >>= 1) v += __shfl_down(v, off);
    __shared__ float wsum[4];
    int lane = t & 63, wid = t >> 6;
    if (lane == 0) wsum[wid] = v;
    __syncthreads();
    if (t == 0) {
        partial[blockIdx.x] = (double)wsum[0] + (double)wsum[1]
                            + (double)wsum[2] + (double)wsum[3];
    }
}

__global__ __launch_bounds__(256) void ciou_finalize(
    const double* __restrict__ partial, float* __restrict__ out,
    int nparts, int nbatch)
{
    double v = 0.0;
    for (int j = threadIdx.x; j < nparts; j += 256) v += partial[j];
    #pragma unroll
    for (int off = 32; off > 0; off >>= 1) v += __shfl_down(v, off);
    __shared__ double s[4];
    int lane = threadIdx.x & 63, wid = threadIdx.x >> 6;
    if (lane == 0) s[wid] = v;
    __syncthreads();
    if (threadIdx.x == 0)
        out[0] = (float)((s[0] + s[1] + s[2] + s[3]) / (double)nbatch);
}

extern "C" void kernel_launch(void* const* d_in, const int* in_sizes, int n_in,
                              void* d_out, int out_size, void* d_ws, size_t ws_size,
                              hipStream_t stream) {
    const float* a = (const float*)d_in[0];
    const float* b = (const float*)d_in[1];
    float* out = (float*)d_out;
    int nbatch = in_sizes[0] / 16;
    int nblocks = (nbatch + TPB - 1) / TPB;
    int tail = (nblocks * TPB != nbatch) ? 1 : 0;   // 262144: tail==0
    double* partial = (double*)d_ws;   // fully overwritten each call; no memset
    ciou_main<<<nblocks, TPB, 0, stream>>>(a, b, partial, nbatch, tail);
    ciou_finalize<<<1, 256, 0, stream>>>(partial, out, nblocks, nbatch);
}